// Round 13
// baseline (2368.736 us; speedup 1.0000x reference)
//
#include <hip/hip_runtime.h>
#include <math.h>

// ---------- helpers ----------
__device__ __forceinline__ float wsum64(float v) {
#pragma unroll
  for (int m = 32; m > 0; m >>= 1) v += __shfl_xor(v, m, 64);
  return v;
}
__device__ __forceinline__ float silu_f(float x) { return x / (1.0f + __expf(-x)); }

// LayerNorm across a 64-lane wave; two reduce chains explicitly interleaved
__device__ __forceinline__ float ln64(float v, float g, float b) {
  float s = v, s2 = v * v;
#pragma unroll
  for (int m = 32; m > 0; m >>= 1) {
    s  += __shfl_xor(s,  m, 64);
    s2 += __shfl_xor(s2, m, 64);
  }
  float mean = s * 0.015625f;
  float var  = fmaxf(s2 * 0.015625f - mean * mean, 0.0f);
  return (v - mean) * rsqrtf(var + 1e-5f) * g + b;
}

// ---------- node embedding: h = silu(LN(x @ ne_w + ne_b)) ----------
__global__ __launch_bounds__(256) void k_node_embed(
    const float* __restrict__ x, const float* __restrict__ W,
    const float* __restrict__ b, const float* __restrict__ g,
    const float* __restrict__ be, float* __restrict__ h, int n) {
  int row = (blockIdx.x * 256 + threadIdx.x) >> 6;
  int j = threadIdx.x & 63;
  if (row >= n) return;
  const float* xr = x + (size_t)row * 16;
  float acc = b[j];
#pragma unroll
  for (int k = 0; k < 16; k += 4) {
    float4 xv = *(const float4*)&xr[k];
    acc += xv.x * W[(k + 0) * 64 + j] + xv.y * W[(k + 1) * 64 + j] +
           xv.z * W[(k + 2) * 64 + j] + xv.w * W[(k + 3) * 64 + j];
  }
  float v = ln64(acc, g[j], be[j]);
  h[(size_t)row * 64 + j] = silu_f(v);
}

// ---------- edge embedding (ONCE, layer-independent): ebuf = silu(LN(ea@eeW)) ----------
__global__ __launch_bounds__(256) void k_edge_embed(
    const float* __restrict__ ea, const float* __restrict__ eeW,
    const float* __restrict__ eeB, const float* __restrict__ eeG,
    const float* __restrict__ eeBe, float* __restrict__ ebuf, int nedges) {
  __shared__ float sEA[4][32];         // per-wave 4 edges x 8 attrs

  const int wv = threadIdx.x >> 6;
  const int j  = threadIdx.x & 63;
  const int ebase = (blockIdx.x * 4 + wv) * 4;
  if (ebase >= nedges) return;

  if (j < 32) {
    long long gi = (long long)ebase * 8 + j;
    long long gmax = (long long)nedges * 8 - 1;
    if (gi > gmax) gi = gmax;
    sEA[wv][j] = ea[gi];               // same-wave write->read: ordered
  }

  float ewc[8];
#pragma unroll
  for (int k = 0; k < 8; ++k) ewc[k] = eeW[k * 64 + j];
  const float eb = eeB[j], eg = eeG[j], ebe = eeBe[j];

#pragma unroll
  for (int e = 0; e < 4; ++e) {
    const float* ar = &sEA[wv][e * 8];
    float ev = eb;
#pragma unroll
    for (int k = 0; k < 8; ++k) ev += ar[k] * ewc[k];
    ev = silu_f(ln64(ev, eg, ebe));
    if (ebase + e < nedges) ebuf[(size_t)(ebase + e) * 64 + j] = ev;
  }
}

// ---------- edge message (r12 structure, EPW=8) ----------
// m = LN(silu(hw1[dst] + hw2[src] + e@W3 + msg_b)); agg[dst] += m
// e-rows staged coalesced from ebuf (2x float4/lane); W3 direct global (L1);
// gathers issued first, consumed only in epilogue (MAC hides latency).
#define EPW 8
__global__ __launch_bounds__(256) void k_edge_msg_pre2(
    const float* __restrict__ ebuf, const float* __restrict__ W3,
    const float* __restrict__ msgB, const float* __restrict__ msgG,
    const float* __restrict__ msgBe,
    const float* __restrict__ hw1, const float* __restrict__ hw2,
    const int* __restrict__ srcI, const int* __restrict__ dstI,
    float* __restrict__ agg, int nedges) {
  __shared__ float sE[4][EPW][64];     // 8 KB

  const int wv = threadIdx.x >> 6;
  const int j  = threadIdx.x & 63;
  const int ebase = (blockIdx.x * 4 + wv) * EPW;
  if (ebase >= nedges) return;

  // coalesced e-row staging: 8 edges x 64 floats = 512 floats per wave.
  // lane j covers offsets j*4 and 256+j*4 (same-wave write->read: ordered)
  {
    const long long gmax = (long long)nedges * 64 - 4;
    long long g0 = (long long)ebase * 64 + j * 4;
    long long g1i = g0 + 256;
    if (g0 > gmax) g0 = gmax;
    if (g1i > gmax) g1i = gmax;
    float4 v0 = *(const float4*)&ebuf[g0];
    float4 v1 = *(const float4*)&ebuf[g1i];
    *(float4*)&sE[wv][j >> 4][(j & 15) * 4] = v0;
    *(float4*)&sE[wv][4 + (j >> 4)][(j & 15) * 4] = v1;
  }

  // gathers issued up-front; results not needed until epilogue
  int dIdx[EPW];
  float g1[EPW], g2[EPW];
#pragma unroll
  for (int e = 0; e < EPW; ++e) {
    int ce = min(ebase + e, nedges - 1);
    int s = srcI[ce];
    dIdx[e] = dstI[ce];
    g1[e] = hw1[(size_t)dIdx[e] * 64 + j];
    g2[e] = hw2[(size_t)s * 64 + j];
  }

  // MAC from LDS + L1-resident W3 (4 W3 rows shared across 8 edges)
  float macc[EPW] = {0.f, 0.f, 0.f, 0.f, 0.f, 0.f, 0.f, 0.f};
#pragma unroll
  for (int k = 0; k < 64; k += 4) {
    float w0 = W3[(k + 0) * 64 + j];
    float w1 = W3[(k + 1) * 64 + j];
    float w2 = W3[(k + 2) * 64 + j];
    float w3 = W3[(k + 3) * 64 + j];
#pragma unroll
    for (int e = 0; e < EPW; ++e) {
      float4 ev4 = *(const float4*)&sE[wv][e][k];
      macc[e] += ev4.x * w0 + ev4.y * w1 + ev4.z * w2 + ev4.w * w3;
    }
  }

  // epilogue: fold gathers + bias, silu, LN, scatter-add
  const float bj = msgB[j], mg = msgG[j], mbe = msgBe[j];
#pragma unroll
  for (int e = 0; e < EPW; ++e) {
    float m = ln64(silu_f(macc[e] + g1[e] + g2[e] + bj), mg, mbe);
    if (ebase + e < nedges) unsafeAtomicAdd(&agg[(size_t)dIdx[e] * 64 + j], m);
  }
}

// ---------- edge message FALLBACK (ws too small): r9 proven kernel, EPW=4 ----------
#define EPWF 4
__global__ __launch_bounds__(256) void k_edge_msg_fb(
    const float* __restrict__ ea, const float* __restrict__ eeW,
    const float* __restrict__ eeB, const float* __restrict__ eeG,
    const float* __restrict__ eeBe,
    const float* __restrict__ W3, const float* __restrict__ msgB,
    const float* __restrict__ msgG, const float* __restrict__ msgBe,
    const float* __restrict__ hw1, const float* __restrict__ hw2,
    const int* __restrict__ srcI, const int* __restrict__ dstI,
    float* __restrict__ agg, int nedges) {
  __shared__ float sE[4][EPWF][64];
  __shared__ float sEA[4][EPWF * 8];

  const int wv = threadIdx.x >> 6;
  const int j  = threadIdx.x & 63;
  const int ebase = (blockIdx.x * 4 + wv) * EPWF;
  if (ebase >= nedges) return;

  if (j < 32) {
    long long gi = (long long)ebase * 8 + j;
    long long gmax = (long long)nedges * 8 - 1;
    if (gi > gmax) gi = gmax;
    sEA[wv][j] = ea[gi];
  }

  const float bj = msgB[j];
  int dIdx[EPWF];
  float acc[EPWF];
#pragma unroll
  for (int e = 0; e < EPWF; ++e) {
    int ce = min(ebase + e, nedges - 1);
    int s = srcI[ce];
    dIdx[e] = dstI[ce];
    acc[e] = hw1[(size_t)dIdx[e] * 64 + j] + hw2[(size_t)s * 64 + j] + bj;
  }
  {
    float ewc[8];
#pragma unroll
    for (int k = 0; k < 8; ++k) ewc[k] = eeW[k * 64 + j];
    const float eb = eeB[j], eg = eeG[j], ebe = eeBe[j];
#pragma unroll
    for (int e = 0; e < EPWF; ++e) {
      const float* ar = &sEA[wv][e * 8];
      float ev = eb;
#pragma unroll
      for (int k = 0; k < 8; ++k) ev += ar[k] * ewc[k];
      ev = silu_f(ln64(ev, eg, ebe));
      sE[wv][e][j] = ev;
    }
  }
#pragma unroll
  for (int k = 0; k < 64; k += 4) {
    float w0 = W3[(k + 0) * 64 + j];
    float w1 = W3[(k + 1) * 64 + j];
    float w2 = W3[(k + 2) * 64 + j];
    float w3 = W3[(k + 3) * 64 + j];
#pragma unroll
    for (int e = 0; e < EPWF; ++e) {
      float4 ev4 = *(const float4*)&sE[wv][e][k];
      acc[e] += ev4.x * w0 + ev4.y * w1 + ev4.z * w2 + ev4.w * w3;
    }
  }
  const float mg = msgG[j], mbe = msgBe[j];
#pragma unroll
  for (int e = 0; e < EPWF; ++e) {
    float m = ln64(silu_f(acc[e]), mg, mbe);
    if (ebase + e < nedges) unsafeAtomicAdd(&agg[(size_t)dIdx[e] * 64 + j], m);
  }
}

// ---------- per-node msg weights: hw1 = h@W[0:64], hw2 = h@W[64:128] ----------
__global__ __launch_bounds__(256) void k_node_msgw(
    const float* __restrict__ h, const float* __restrict__ W,
    float* __restrict__ hw1, float* __restrict__ hw2, int n) {
  int row = (blockIdx.x * 256 + threadIdx.x) >> 6;
  int j = threadIdx.x & 63;
  if (row >= n) return;
  const float* hr = h + (size_t)row * 64;
  float a1 = 0.0f, a2 = 0.0f;
#pragma unroll
  for (int k = 0; k < 64; k += 4) {
    float4 hv = *(const float4*)&hr[k];
    a1 += hv.x * W[(k + 0) * 64 + j] + hv.y * W[(k + 1) * 64 + j] +
          hv.z * W[(k + 2) * 64 + j] + hv.w * W[(k + 3) * 64 + j];
    a2 += hv.x * W[(64 + k + 0) * 64 + j] + hv.y * W[(64 + k + 1) * 64 + j] +
          hv.z * W[(64 + k + 2) * 64 + j] + hv.w * W[(64 + k + 3) * 64 + j];
  }
  hw1[(size_t)row * 64 + j] = a1;
  hw2[(size_t)row * 64 + j] = a2;
}

// ---------- update IN-PLACE: h = LN(LN(silu((h+agg)@W+b)) + h) ----------
__global__ __launch_bounds__(256) void k_node_update_ip(
    float* h, const float* __restrict__ agg,
    const float* __restrict__ W, const float* __restrict__ b,
    const float* __restrict__ ug, const float* __restrict__ ube,
    const float* __restrict__ ng, const float* __restrict__ nbe, int n) {
  int row = (blockIdx.x * 256 + threadIdx.x) >> 6;
  int j = threadIdx.x & 63;
  if (row >= n) return;
  float* hr = h + (size_t)row * 64;
  const float* ar = agg + (size_t)row * 64;
  float acc = b[j];
  float hj = hr[j];
#pragma unroll
  for (int k = 0; k < 64; k += 4) {
    float4 hv = *(const float4*)&hr[k];
    float4 av = *(const float4*)&ar[k];
    acc += (hv.x + av.x) * W[(k + 0) * 64 + j] + (hv.y + av.y) * W[(k + 1) * 64 + j] +
           (hv.z + av.z) * W[(k + 2) * 64 + j] + (hv.w + av.w) * W[(k + 3) * 64 + j];
  }
  float u = ln64(silu_f(acc), ug[j], ube[j]);
  hr[j] = ln64(u + hj, ng[j], nbe[j]);
}

// ---------- pooling ----------
__global__ __launch_bounds__(256) void k_pool(
    const float* __restrict__ h, const int* __restrict__ batch,
    float* __restrict__ gsum, float* __restrict__ gcnt, int n) {
  int row = (blockIdx.x * 256 + threadIdx.x) >> 6;
  int j = threadIdx.x & 63;
  if (row >= n) return;
  int b = batch[row];
  unsafeAtomicAdd(&gsum[(size_t)b * 64 + j], h[(size_t)row * 64 + j]);
  if (j == 0) unsafeAtomicAdd(&gcnt[b], 1.0f);
}

// ---------- head: out = silu(LN(g@h1_w+b)) @ h2_w + h2_b ----------
__global__ __launch_bounds__(64) void k_head(
    const float* __restrict__ gsum, const float* __restrict__ gcnt,
    const float* __restrict__ w1, const float* __restrict__ b1,
    const float* __restrict__ g1, const float* __restrict__ be1,
    const float* __restrict__ w2, const float* __restrict__ b2,
    float* __restrict__ out, int ngraphs) {
  int gidx = blockIdx.x;
  int j = threadIdx.x;
  if (gidx >= ngraphs) return;
  __shared__ float sg[64];
  float cnt = fmaxf(gcnt[gidx], 1.0f);
  sg[j] = gsum[(size_t)gidx * 64 + j] / cnt;
  float acc = 0.0f;
  if (j < 32) {
    acc = b1[j];
#pragma unroll 8
    for (int k = 0; k < 64; ++k) acc += sg[k] * w1[k * 32 + j];
  }
  float s = acc, s2 = acc * acc;
#pragma unroll
  for (int m = 16; m > 0; m >>= 1) {
    s  += __shfl_xor(s,  m, 64);
    s2 += __shfl_xor(s2, m, 64);
  }
  float mean = s * 0.03125f;
  float var  = fmaxf(s2 * 0.03125f - mean * mean, 0.0f);
  float z = 0.0f;
  if (j < 32) {
    float nv = (acc - mean) * rsqrtf(var + 1e-5f) * g1[j] + be1[j];
    z = silu_f(nv) * w2[j];
  }
  float tot = wsum64(z);
  if (j == 0) out[gidx] = tot + b2[0];
}

// ---------- launch ----------
extern "C" void kernel_launch(void* const* d_in, const int* in_sizes, int n_in,
                              void* d_out, int out_size, void* d_ws, size_t ws_size,
                              hipStream_t stream) {
  const float* x      = (const float*)d_in[0];
  const float* ea     = (const float*)d_in[1];
  const float* ne_w   = (const float*)d_in[2];
  const float* ne_b   = (const float*)d_in[3];
  const float* ne_g   = (const float*)d_in[4];
  const float* ne_be  = (const float*)d_in[5];
  const float* ee_w   = (const float*)d_in[6];
  const float* ee_b   = (const float*)d_in[7];
  const float* ee_g   = (const float*)d_in[8];
  const float* ee_be  = (const float*)d_in[9];
  const float* msg_w  = (const float*)d_in[10];
  const float* msg_b  = (const float*)d_in[11];
  const float* msg_g  = (const float*)d_in[12];
  const float* msg_be = (const float*)d_in[13];
  const float* upd_w  = (const float*)d_in[14];
  const float* upd_b  = (const float*)d_in[15];
  const float* upd_g  = (const float*)d_in[16];
  const float* upd_be = (const float*)d_in[17];
  const float* nrm_g  = (const float*)d_in[18];
  const float* nrm_be = (const float*)d_in[19];
  const float* h1_w   = (const float*)d_in[20];
  const float* h1_b   = (const float*)d_in[21];
  const float* h1_g   = (const float*)d_in[22];
  const float* h1_be  = (const float*)d_in[23];
  const float* h2_w   = (const float*)d_in[24];
  const float* h2_b   = (const float*)d_in[25];
  const int*   ei     = (const int*)d_in[26];
  const int*   batch  = (const int*)d_in[27];
  float* out = (float*)d_out;

  const int N = in_sizes[0] / 16;
  const int E = in_sizes[1] / 8;
  const int G = out_size;
  const int* srcI = ei;       // edge_index[0] = src (x_j)
  const int* dstI = ei + E;   // edge_index[1] = dst (x_i)

  float* ws  = (float*)d_ws;
  float* h    = ws;
  float* hw1  = h   + (size_t)N * 64;
  float* hw2  = hw1 + (size_t)N * 64;
  float* agg  = hw2 + (size_t)N * 64;
  float* gsum = agg + (size_t)N * 64;
  float* gcnt = gsum + (size_t)G * 64;
  float* ebuf = gcnt + G;     // pre path: [E,64] edge embeddings

  const size_t fixed_floats = (size_t)N * 64 * 4 + (size_t)G * 64 + G;
  const bool pre = (ws_size / 4 >= fixed_floats + (size_t)E * 64);

  const int nblk = (N + 3) / 4;                        // 4 node rows per block
  const int eblkE = (E + 15) / 16;                     // edge-embed blocks
  const int eblk = (E + 4 * EPW - 1) / (4 * EPW);      // 32 edges per block
  const int eblkF = (E + 4 * EPWF - 1) / (4 * EPWF);   // fallback blocks

  k_node_embed<<<nblk, 256, 0, stream>>>(x, ne_w, ne_b, ne_g, ne_be, h, N);
  if (pre)
    k_edge_embed<<<eblkE, 256, 0, stream>>>(ea, ee_w, ee_b, ee_g, ee_be, ebuf, E);

  for (int l = 0; l < 2; ++l) {
    const float* Wl = msg_w + (size_t)l * 192 * 64;
    k_node_msgw<<<nblk, 256, 0, stream>>>(h, Wl, hw1, hw2, N);
    hipMemsetAsync(agg, 0, (size_t)N * 64 * sizeof(float), stream);
    if (pre) {
      k_edge_msg_pre2<<<eblk, 256, 0, stream>>>(
          ebuf, Wl + 128 * 64, msg_b + l * 64, msg_g + l * 64, msg_be + l * 64,
          hw1, hw2, srcI, dstI, agg, E);
    } else {
      k_edge_msg_fb<<<eblkF, 256, 0, stream>>>(
          ea, ee_w, ee_b, ee_g, ee_be,
          Wl + 128 * 64, msg_b + l * 64, msg_g + l * 64, msg_be + l * 64,
          hw1, hw2, srcI, dstI, agg, E);
    }
    k_node_update_ip<<<nblk, 256, 0, stream>>>(
        h, agg, upd_w + (size_t)l * 64 * 64,
        upd_b + l * 64, upd_g + l * 64, upd_be + l * 64,
        nrm_g + l * 64, nrm_be + l * 64, N);
  }

  hipMemsetAsync(gsum, 0, ((size_t)G * 64 + G) * sizeof(float), stream);
  k_pool<<<nblk, 256, 0, stream>>>(h, batch, gsum, gcnt, N);
  k_head<<<G, 64, 0, stream>>>(gsum, gcnt, h1_w, h1_b, h1_g, h1_be, h2_w, h2_b, out, G);
}

// Round 14
// 1193.067 us; speedup vs baseline: 1.9854x; 1.9854x over previous
//
#include <hip/hip_runtime.h>
#include <math.h>

// ---------- helpers ----------
__device__ __forceinline__ float silu_f(float x) { return x / (1.0f + __expf(-x)); }

// LayerNorm across a 64-lane wave; two reduce chains explicitly interleaved
__device__ __forceinline__ float ln64(float v, float g, float b) {
  float s = v, s2 = v * v;
#pragma unroll
  for (int m = 32; m > 0; m >>= 1) {
    s  += __shfl_xor(s,  m, 64);
    s2 += __shfl_xor(s2, m, 64);
  }
  float mean = s * 0.015625f;
  float var  = fmaxf(s2 * 0.015625f - mean * mean, 0.0f);
  return (v - mean) * rsqrtf(var + 1e-5f) * g + b;
}

// ---------- FUSED: node embed -> h, hw1/hw2(layer0), agg=0 ----------
__global__ __launch_bounds__(256) void k_embed_msgw(
    const float* __restrict__ x, const float* __restrict__ neW,
    const float* __restrict__ neB, const float* __restrict__ neG,
    const float* __restrict__ neBe, const float* __restrict__ W,   // msg_w[0], rows 0..127
    float* __restrict__ h, float* __restrict__ hw1, float* __restrict__ hw2,
    float* __restrict__ agg, int n) {
  __shared__ float sRow[4][64];
  const int row = (blockIdx.x * 256 + threadIdx.x) >> 6;
  const int wv = threadIdx.x >> 6;
  const int j  = threadIdx.x & 63;
  if (row >= n) return;

  const float* xr = x + (size_t)row * 16;
  float acc = neB[j];
#pragma unroll
  for (int k = 0; k < 16; k += 4) {
    float4 xv = *(const float4*)&xr[k];
    acc += xv.x * neW[(k + 0) * 64 + j] + xv.y * neW[(k + 1) * 64 + j] +
           xv.z * neW[(k + 2) * 64 + j] + xv.w * neW[(k + 3) * 64 + j];
  }
  float hv = silu_f(ln64(acc, neG[j], neBe[j]));
  h[(size_t)row * 64 + j] = hv;
  agg[(size_t)row * 64 + j] = 0.0f;
  sRow[wv][j] = hv;                    // same-wave write->read: ordered

  float a1 = 0.0f, a2 = 0.0f;
#pragma unroll
  for (int k = 0; k < 64; k += 4) {
    float4 r = *(const float4*)&sRow[wv][k];
    a1 += r.x * W[(k + 0) * 64 + j] + r.y * W[(k + 1) * 64 + j] +
          r.z * W[(k + 2) * 64 + j] + r.w * W[(k + 3) * 64 + j];
    a2 += r.x * W[(64 + k + 0) * 64 + j] + r.y * W[(64 + k + 1) * 64 + j] +
          r.z * W[(64 + k + 2) * 64 + j] + r.w * W[(64 + k + 3) * 64 + j];
  }
  hw1[(size_t)row * 64 + j] = a1;
  hw2[(size_t)row * 64 + j] = a2;
}

// ---------- edge embedding (ONCE, layer-independent): ebuf = silu(LN(ea@eeW)) ----------
__global__ __launch_bounds__(256) void k_edge_embed(
    const float* __restrict__ ea, const float* __restrict__ eeW,
    const float* __restrict__ eeB, const float* __restrict__ eeG,
    const float* __restrict__ eeBe, float* __restrict__ ebuf, int nedges) {
  __shared__ float sEA[4][32];         // per-wave 4 edges x 8 attrs

  const int wv = threadIdx.x >> 6;
  const int j  = threadIdx.x & 63;
  const int ebase = (blockIdx.x * 4 + wv) * 4;
  if (ebase >= nedges) return;

  if (j < 32) {
    long long gi = (long long)ebase * 8 + j;
    long long gmax = (long long)nedges * 8 - 1;
    if (gi > gmax) gi = gmax;
    sEA[wv][j] = ea[gi];               // same-wave write->read: ordered
  }

  float ewc[8];
#pragma unroll
  for (int k = 0; k < 8; ++k) ewc[k] = eeW[k * 64 + j];
  const float eb = eeB[j], eg = eeG[j], ebe = eeBe[j];

#pragma unroll
  for (int e = 0; e < 4; ++e) {
    const float* ar = &sEA[wv][e * 8];
    float ev = eb;
#pragma unroll
    for (int k = 0; k < 8; ++k) ev += ar[k] * ewc[k];
    ev = silu_f(ln64(ev, eg, ebe));
    if (ebase + e < nedges) ebuf[(size_t)(ebase + e) * 64 + j] = ev;
  }
}

// ---------- edge message (r12 proven structure, EPW=4) ----------
// m = LN(silu(hw1[dst] + hw2[src] + e@W3 + msg_b)); agg[dst] += m
#define EPW 4
__global__ __launch_bounds__(256) void k_edge_msg_pre2(
    const float* __restrict__ ebuf, const float* __restrict__ W3,
    const float* __restrict__ msgB, const float* __restrict__ msgG,
    const float* __restrict__ msgBe,
    const float* __restrict__ hw1, const float* __restrict__ hw2,
    const int* __restrict__ srcI, const int* __restrict__ dstI,
    float* __restrict__ agg, int nedges) {
  __shared__ float sE[4][EPW][64];     // 4 KB

  const int wv = threadIdx.x >> 6;
  const int j  = threadIdx.x & 63;
  const int ebase = (blockIdx.x * 4 + wv) * EPW;
  if (ebase >= nedges) return;

  // coalesced e-row staging: lane j -> edge (j>>4), cols (j&15)*4 .. +3
  {
    long long gi = (long long)ebase * 64 + j * 4;
    long long gmax = (long long)nedges * 64 - 4;
    if (gi > gmax) gi = gmax;
    float4 v = *(const float4*)&ebuf[gi];
    *(float4*)&sE[wv][j >> 4][(j & 15) * 4] = v;   // same-wave: ordered
  }

  // gathers issued up-front; results not needed until epilogue
  int dIdx[EPW];
  float g1[EPW], g2[EPW];
#pragma unroll
  for (int e = 0; e < EPW; ++e) {
    int ce = min(ebase + e, nedges - 1);
    int s = srcI[ce];
    dIdx[e] = dstI[ce];
    g1[e] = hw1[(size_t)dIdx[e] * 64 + j];
    g2[e] = hw2[(size_t)s * 64 + j];
  }

  // MAC from LDS + L1-resident W3
  float macc[EPW] = {0.f, 0.f, 0.f, 0.f};
#pragma unroll
  for (int k = 0; k < 64; k += 4) {
    float w0 = W3[(k + 0) * 64 + j];
    float w1 = W3[(k + 1) * 64 + j];
    float w2 = W3[(k + 2) * 64 + j];
    float w3 = W3[(k + 3) * 64 + j];
#pragma unroll
    for (int e = 0; e < EPW; ++e) {
      float4 ev4 = *(const float4*)&sE[wv][e][k];
      macc[e] += ev4.x * w0 + ev4.y * w1 + ev4.z * w2 + ev4.w * w3;
    }
  }

  // epilogue: fold gathers + bias, silu, LN, scatter-add
  const float bj = msgB[j], mg = msgG[j], mbe = msgBe[j];
#pragma unroll
  for (int e = 0; e < EPW; ++e) {
    float m = ln64(silu_f(macc[e] + g1[e] + g2[e] + bj), mg, mbe);
    if (ebase + e < nedges) unsafeAtomicAdd(&agg[(size_t)dIdx[e] * 64 + j], m);
  }
}

// ---------- edge message FALLBACK (ws too small): r9 proven kernel ----------
__global__ __launch_bounds__(256) void k_edge_msg_fb(
    const float* __restrict__ ea, const float* __restrict__ eeW,
    const float* __restrict__ eeB, const float* __restrict__ eeG,
    const float* __restrict__ eeBe,
    const float* __restrict__ W3, const float* __restrict__ msgB,
    const float* __restrict__ msgG, const float* __restrict__ msgBe,
    const float* __restrict__ hw1, const float* __restrict__ hw2,
    const int* __restrict__ srcI, const int* __restrict__ dstI,
    float* __restrict__ agg, int nedges) {
  __shared__ float sE[4][EPW][64];
  __shared__ float sEA[4][EPW * 8];

  const int wv = threadIdx.x >> 6;
  const int j  = threadIdx.x & 63;
  const int ebase = (blockIdx.x * 4 + wv) * EPW;
  if (ebase >= nedges) return;

  if (j < 32) {
    long long gi = (long long)ebase * 8 + j;
    long long gmax = (long long)nedges * 8 - 1;
    if (gi > gmax) gi = gmax;
    sEA[wv][j] = ea[gi];
  }

  const float bj = msgB[j];
  int dIdx[EPW];
  float acc[EPW];
#pragma unroll
  for (int e = 0; e < EPW; ++e) {
    int ce = min(ebase + e, nedges - 1);
    int s = srcI[ce];
    dIdx[e] = dstI[ce];
    acc[e] = hw1[(size_t)dIdx[e] * 64 + j] + hw2[(size_t)s * 64 + j] + bj;
  }
  {
    float ewc[8];
#pragma unroll
    for (int k = 0; k < 8; ++k) ewc[k] = eeW[k * 64 + j];
    const float eb = eeB[j], eg = eeG[j], ebe = eeBe[j];
#pragma unroll
    for (int e = 0; e < EPW; ++e) {
      const float* ar = &sEA[wv][e * 8];
      float ev = eb;
#pragma unroll
      for (int k = 0; k < 8; ++k) ev += ar[k] * ewc[k];
      ev = silu_f(ln64(ev, eg, ebe));
      sE[wv][e][j] = ev;
    }
  }
#pragma unroll
  for (int k = 0; k < 64; k += 4) {
    float w0 = W3[(k + 0) * 64 + j];
    float w1 = W3[(k + 1) * 64 + j];
    float w2 = W3[(k + 2) * 64 + j];
    float w3 = W3[(k + 3) * 64 + j];
#pragma unroll
    for (int e = 0; e < EPW; ++e) {
      float4 ev4 = *(const float4*)&sE[wv][e][k];
      acc[e] += ev4.x * w0 + ev4.y * w1 + ev4.z * w2 + ev4.w * w3;
    }
  }
  const float mg = msgG[j], mbe = msgBe[j];
#pragma unroll
  for (int e = 0; e < EPW; ++e) {
    float m = ln64(silu_f(acc[e]), mg, mbe);
    if (ebase + e < nedges) unsafeAtomicAdd(&agg[(size_t)dIdx[e] * 64 + j], m);
  }
}

// ---------- FUSED: update(in-place) -> hw1/hw2(next layer), agg=0 ----------
__global__ __launch_bounds__(256) void k_update_msgw(
    float* h, float* agg,                       // agg read then zeroed
    const float* __restrict__ W, const float* __restrict__ b,
    const float* __restrict__ ug, const float* __restrict__ ube,
    const float* __restrict__ ng, const float* __restrict__ nbe,
    const float* __restrict__ Wn,               // next layer msg_w rows 0..127
    float* __restrict__ hw1, float* __restrict__ hw2, int n) {
  __shared__ float sRow[4][64];
  const int row = (blockIdx.x * 256 + threadIdx.x) >> 6;
  const int wv = threadIdx.x >> 6;
  const int j  = threadIdx.x & 63;
  if (row >= n) return;

  float* hr = h + (size_t)row * 64;
  float* ar = agg + (size_t)row * 64;
  float acc = b[j];
  float hj = hr[j];
#pragma unroll
  for (int k = 0; k < 64; k += 4) {
    float4 hv = *(const float4*)&hr[k];
    float4 av = *(const float4*)&ar[k];
    acc += (hv.x + av.x) * W[(k + 0) * 64 + j] + (hv.y + av.y) * W[(k + 1) * 64 + j] +
           (hv.z + av.z) * W[(k + 2) * 64 + j] + (hv.w + av.w) * W[(k + 3) * 64 + j];
  }
  float u = ln64(silu_f(acc), ug[j], ube[j]);
  float hn = ln64(u + hj, ng[j], nbe[j]);
  hr[j] = hn;
  ar[j] = 0.0f;                        // zero agg for next layer
  sRow[wv][j] = hn;                    // same-wave ordered

  float a1 = 0.0f, a2 = 0.0f;
#pragma unroll
  for (int k = 0; k < 64; k += 4) {
    float4 r = *(const float4*)&sRow[wv][k];
    a1 += r.x * Wn[(k + 0) * 64 + j] + r.y * Wn[(k + 1) * 64 + j] +
          r.z * Wn[(k + 2) * 64 + j] + r.w * Wn[(k + 3) * 64 + j];
    a2 += r.x * Wn[(64 + k + 0) * 64 + j] + r.y * Wn[(64 + k + 1) * 64 + j] +
          r.z * Wn[(64 + k + 2) * 64 + j] + r.w * Wn[(64 + k + 3) * 64 + j];
  }
  hw1[(size_t)row * 64 + j] = a1;
  hw2[(size_t)row * 64 + j] = a2;
}

// ---------- FUSED: final update(in-place) -> pool atomics ----------
__global__ __launch_bounds__(256) void k_update_pool(
    float* h, const float* __restrict__ agg,
    const float* __restrict__ W, const float* __restrict__ b,
    const float* __restrict__ ug, const float* __restrict__ ube,
    const float* __restrict__ ng, const float* __restrict__ nbe,
    const int* __restrict__ batch, float* __restrict__ gsum,
    float* __restrict__ gcnt, int n) {
  const int row = (blockIdx.x * 256 + threadIdx.x) >> 6;
  const int j  = threadIdx.x & 63;
  if (row >= n) return;

  float* hr = h + (size_t)row * 64;
  const float* ar = agg + (size_t)row * 64;
  float acc = b[j];
  float hj = hr[j];
#pragma unroll
  for (int k = 0; k < 64; k += 4) {
    float4 hv = *(const float4*)&hr[k];
    float4 av = *(const float4*)&ar[k];
    acc += (hv.x + av.x) * W[(k + 0) * 64 + j] + (hv.y + av.y) * W[(k + 1) * 64 + j] +
           (hv.z + av.z) * W[(k + 2) * 64 + j] + (hv.w + av.w) * W[(k + 3) * 64 + j];
  }
  float u = ln64(silu_f(acc), ug[j], ube[j]);
  float hn = ln64(u + hj, ng[j], nbe[j]);

  int bb = batch[row];
  unsafeAtomicAdd(&gsum[(size_t)bb * 64 + j], hn);
  if (j == 0) unsafeAtomicAdd(&gcnt[bb], 1.0f);
}

// ---------- head: out = silu(LN(g@h1_w+b)) @ h2_w + h2_b ----------
__global__ __launch_bounds__(64) void k_head(
    const float* __restrict__ gsum, const float* __restrict__ gcnt,
    const float* __restrict__ w1, const float* __restrict__ b1,
    const float* __restrict__ g1, const float* __restrict__ be1,
    const float* __restrict__ w2, const float* __restrict__ b2,
    float* __restrict__ out, int ngraphs) {
  int gidx = blockIdx.x;
  int j = threadIdx.x;
  if (gidx >= ngraphs) return;
  __shared__ float sg[64];
  float cnt = fmaxf(gcnt[gidx], 1.0f);
  sg[j] = gsum[(size_t)gidx * 64 + j] / cnt;
  float acc = 0.0f;
  if (j < 32) {
    acc = b1[j];
#pragma unroll 8
    for (int k = 0; k < 64; ++k) acc += sg[k] * w1[k * 32 + j];
  }
  float s = acc, s2 = acc * acc;
#pragma unroll
  for (int m = 16; m > 0; m >>= 1) {
    s  += __shfl_xor(s,  m, 64);
    s2 += __shfl_xor(s2, m, 64);
  }
  float mean = s * 0.03125f;
  float var  = fmaxf(s2 * 0.03125f - mean * mean, 0.0f);
  float z = 0.0f;
  if (j < 32) {
    float nv = (acc - mean) * rsqrtf(var + 1e-5f) * g1[j] + be1[j];
    z = silu_f(nv) * w2[j];
  }
#pragma unroll
  for (int m = 32; m > 0; m >>= 1) z += __shfl_xor(z, m, 64);
  if (j == 0) out[gidx] = z + b2[0];
}

// ---------- launch ----------
extern "C" void kernel_launch(void* const* d_in, const int* in_sizes, int n_in,
                              void* d_out, int out_size, void* d_ws, size_t ws_size,
                              hipStream_t stream) {
  const float* x      = (const float*)d_in[0];
  const float* ea     = (const float*)d_in[1];
  const float* ne_w   = (const float*)d_in[2];
  const float* ne_b   = (const float*)d_in[3];
  const float* ne_g   = (const float*)d_in[4];
  const float* ne_be  = (const float*)d_in[5];
  const float* ee_w   = (const float*)d_in[6];
  const float* ee_b   = (const float*)d_in[7];
  const float* ee_g   = (const float*)d_in[8];
  const float* ee_be  = (const float*)d_in[9];
  const float* msg_w  = (const float*)d_in[10];
  const float* msg_b  = (const float*)d_in[11];
  const float* msg_g  = (const float*)d_in[12];
  const float* msg_be = (const float*)d_in[13];
  const float* upd_w  = (const float*)d_in[14];
  const float* upd_b  = (const float*)d_in[15];
  const float* upd_g  = (const float*)d_in[16];
  const float* upd_be = (const float*)d_in[17];
  const float* nrm_g  = (const float*)d_in[18];
  const float* nrm_be = (const float*)d_in[19];
  const float* h1_w   = (const float*)d_in[20];
  const float* h1_b   = (const float*)d_in[21];
  const float* h1_g   = (const float*)d_in[22];
  const float* h1_be  = (const float*)d_in[23];
  const float* h2_w   = (const float*)d_in[24];
  const float* h2_b   = (const float*)d_in[25];
  const int*   ei     = (const int*)d_in[26];
  const int*   batch  = (const int*)d_in[27];
  float* out = (float*)d_out;

  const int N = in_sizes[0] / 16;
  const int E = in_sizes[1] / 8;
  const int G = out_size;
  const int* srcI = ei;       // edge_index[0] = src (x_j)
  const int* dstI = ei + E;   // edge_index[1] = dst (x_i)

  float* ws  = (float*)d_ws;
  float* h    = ws;
  float* hw1  = h   + (size_t)N * 64;
  float* hw2  = hw1 + (size_t)N * 64;
  float* agg  = hw2 + (size_t)N * 64;
  float* gsum = agg + (size_t)N * 64;
  float* gcnt = gsum + (size_t)G * 64;
  float* ebuf = gcnt + G;     // pre path: [E,64] edge embeddings

  const size_t fixed_floats = (size_t)N * 64 * 4 + (size_t)G * 64 + G;
  const bool pre = (ws_size / 4 >= fixed_floats + (size_t)E * 64);

  const int nblk = (N + 3) / 4;                      // 4 node rows per block
  const int eblk = (E + 4 * EPW - 1) / (4 * EPW);    // 16 edges per block

  // embed + msgw(layer0) + agg=0
  k_embed_msgw<<<nblk, 256, 0, stream>>>(
      x, ne_w, ne_b, ne_g, ne_be, msg_w, h, hw1, hw2, agg, N);
  if (pre)
    k_edge_embed<<<eblk, 256, 0, stream>>>(ea, ee_w, ee_b, ee_g, ee_be, ebuf, E);

  // ---- layer 0 ----
  if (pre) {
    k_edge_msg_pre2<<<eblk, 256, 0, stream>>>(
        ebuf, msg_w + 128 * 64, msg_b, msg_g, msg_be,
        hw1, hw2, srcI, dstI, agg, E);
  } else {
    k_edge_msg_fb<<<eblk, 256, 0, stream>>>(
        ea, ee_w, ee_b, ee_g, ee_be,
        msg_w + 128 * 64, msg_b, msg_g, msg_be,
        hw1, hw2, srcI, dstI, agg, E);
  }
  // update(l=0) + msgw(layer1) + agg=0
  k_update_msgw<<<nblk, 256, 0, stream>>>(
      h, agg, upd_w, upd_b, upd_g, upd_be, nrm_g, nrm_be,
      msg_w + (size_t)192 * 64, hw1, hw2, N);

  // ---- layer 1 ----
  if (pre) {
    k_edge_msg_pre2<<<eblk, 256, 0, stream>>>(
        ebuf, msg_w + (size_t)192 * 64 + 128 * 64, msg_b + 64, msg_g + 64,
        msg_be + 64, hw1, hw2, srcI, dstI, agg, E);
  } else {
    k_edge_msg_fb<<<eblk, 256, 0, stream>>>(
        ea, ee_w, ee_b, ee_g, ee_be,
        msg_w + (size_t)192 * 64 + 128 * 64, msg_b + 64, msg_g + 64,
        msg_be + 64, hw1, hw2, srcI, dstI, agg, E);
  }
  hipMemsetAsync(gsum, 0, ((size_t)G * 64 + G) * sizeof(float), stream);
  // update(l=1) + pool
  k_update_pool<<<nblk, 256, 0, stream>>>(
      h, agg, upd_w + (size_t)64 * 64, upd_b + 64, upd_g + 64, upd_be + 64,
      nrm_g + 64, nrm_be + 64, batch, gsum, gcnt, N);

  k_head<<<G, 64, 0, stream>>>(gsum, gcnt, h1_w, h1_b, h1_g, h1_be, h2_w, h2_b, out, G);
}